// Round 2
// baseline (20457.104 us; speedup 1.0000x reference)
//
#include <hip/hip_runtime.h>
#include <hip/hip_bf16.h>

#define NP     100000   // n_paths
#define PLEN   5        // path length
#define NLINKS 10000    // n_links
#define DIM    32       // state dim
#define TITERS 8        // message-passing iterations

// ---------- activation helpers ----------
__device__ __forceinline__ float fast_sigmoid(float v) {
    return 1.0f / (1.0f + __expf(-v));
}
__device__ __forceinline__ float fast_tanh(float v) {
    float e = __expf(-2.0f * fabsf(v));
    float t = (1.0f - e) / (1.0f + e);
    return v >= 0.0f ? t : -t;
}
__device__ __forceinline__ float seluf(float v) {
    const float sc = 1.0507009873554805f;
    const float al = 1.6732632423543772f;
    return v > 0.0f ? sc * v : sc * al * (__expf(v) - 1.0f);
}

// ---------- keras GRUCell (reset_after=True), gate order z,r,n ----------
// x,h held fully in registers; W/U/b accessed with wave-uniform indices
// so the compiler emits scalar (s_load) reads -> FMA-pipe bound.
__device__ __forceinline__ void gru32(const float* __restrict__ W,
                                      const float* __restrict__ U,
                                      const float* __restrict__ b,
                                      const float (&x)[DIM], float (&h)[DIM])
{
    float z[DIM], r[DIM], hn[DIM];
    #pragma unroll
    for (int j = 0; j < DIM; ++j) {
        float sz = b[j]      + b[96 + j];
        float sr = b[32 + j] + b[96 + 32 + j];
        #pragma unroll
        for (int k = 0; k < DIM; ++k) {
            sz += x[k] * W[k * 96 + j]      + h[k] * U[k * 96 + j];
            sr += x[k] * W[k * 96 + 32 + j] + h[k] * U[k * 96 + 32 + j];
        }
        z[j] = fast_sigmoid(sz);
        r[j] = fast_sigmoid(sr);
    }
    #pragma unroll
    for (int j = 0; j < DIM; ++j) {
        float xn = b[64 + j];
        float hg = b[96 + 64 + j];
        #pragma unroll
        for (int k = 0; k < DIM; ++k) {
            xn += x[k] * W[k * 96 + 64 + j];
            hg += h[k] * U[k * 96 + 64 + j];
        }
        hn[j] = fast_tanh(xn + r[j] * hg);
    }
    #pragma unroll
    for (int j = 0; j < DIM; ++j)
        h[j] = z[j] * h[j] + (1.0f - z[j]) * hn[j];
}

// ---------- init: build link_state [NL,32] and path_state [P,32] ----------
__global__ __launch_bounds__(256) void init_kernel(
    const float* __restrict__ cap, const float* __restrict__ pol, const float* __restrict__ wts,
    const float* __restrict__ bw,  const float* __restrict__ tos,
    const float* __restrict__ pk,  const float* __restrict__ avg,
    float* __restrict__ link_state, float* __restrict__ path_state)
{
    int i = blockIdx.x * 256 + threadIdx.x;
    if (i < NLINKS) {
        float row[DIM];
        #pragma unroll
        for (int c = 0; c < DIM; ++c) row[c] = 0.0f;
        row[0] = cap[i]; row[1] = pol[i]; row[2] = wts[i];
        float4* o = (float4*)(link_state + (size_t)i * DIM);
        #pragma unroll
        for (int c = 0; c < 8; ++c) {
            float4 v = { row[4*c], row[4*c+1], row[4*c+2], row[4*c+3] };
            o[c] = v;
        }
    }
    if (i < NP) {
        float row[DIM];
        #pragma unroll
        for (int c = 0; c < DIM; ++c) row[c] = 0.0f;
        row[0] = bw[i]; row[1] = tos[i]; row[2] = pk[i]; row[3] = avg[i];
        float4* o = (float4*)(path_state + (size_t)i * DIM);
        #pragma unroll
        for (int c = 0; c < 8; ++c) {
            float4 v = { row[4*c], row[4*c+1], row[4*c+2], row[4*c+3] };
            o[c] = v;
        }
    }
}

// ---------- path GRU over 5 hops + scatter messages into msg[NL,32] ----------
__global__ __launch_bounds__(64) void path_kernel(
    const int*   __restrict__ links,
    const float* __restrict__ Wp, const float* __restrict__ Up, const float* __restrict__ bp,
    const float* __restrict__ link_state,
    float* __restrict__ path_state,
    float* __restrict__ msg)
{
    int p = blockIdx.x * 64 + threadIdx.x;
    if (p >= NP) return;
    float h[DIM], x[DIM];
    const float4* hv = (const float4*)(path_state + (size_t)p * DIM);
    #pragma unroll
    for (int i = 0; i < 8; ++i) {
        float4 v = hv[i];
        h[4*i] = v.x; h[4*i+1] = v.y; h[4*i+2] = v.z; h[4*i+3] = v.w;
    }
    #pragma unroll 1
    for (int l = 0; l < PLEN; ++l) {
        int link = links[p * PLEN + l];
        const float4* xv = (const float4*)(link_state + (size_t)link * DIM);
        #pragma unroll
        for (int i = 0; i < 8; ++i) {
            float4 v = xv[i];
            x[4*i] = v.x; x[4*i+1] = v.y; x[4*i+2] = v.z; x[4*i+3] = v.w;
        }
        gru32(Wp, Up, bp, x, h);
        float* mrow = msg + (size_t)link * DIM;
        #pragma unroll
        for (int c = 0; c < DIM; ++c)
            __hip_atomic_fetch_add(&mrow[c], h[c], __ATOMIC_RELAXED, __HIP_MEMORY_SCOPE_AGENT);
    }
    float4* ho = (float4*)(path_state + (size_t)p * DIM);
    #pragma unroll
    for (int i = 0; i < 8; ++i) {
        float4 v = { h[4*i], h[4*i+1], h[4*i+2], h[4*i+3] };
        ho[i] = v;
    }
}

// ---------- link GRU ----------
__global__ __launch_bounds__(64) void link_kernel(
    const float* __restrict__ Wl, const float* __restrict__ Ul, const float* __restrict__ bl,
    const float* __restrict__ msg,
    float* __restrict__ link_state)
{
    int i = blockIdx.x * 64 + threadIdx.x;
    if (i >= NLINKS) return;
    float h[DIM], x[DIM];
    const float4* xv = (const float4*)(msg + (size_t)i * DIM);
    const float4* hv = (const float4*)(link_state + (size_t)i * DIM);
    #pragma unroll
    for (int c = 0; c < 8; ++c) {
        float4 a = xv[c];
        x[4*c] = a.x; x[4*c+1] = a.y; x[4*c+2] = a.z; x[4*c+3] = a.w;
        float4 b2 = hv[c];
        h[4*c] = b2.x; h[4*c+1] = b2.y; h[4*c+2] = b2.z; h[4*c+3] = b2.w;
    }
    gru32(Wl, Ul, bl, x, h);
    float4* ho = (float4*)(link_state + (size_t)i * DIM);
    #pragma unroll
    for (int c = 0; c < 8; ++c) {
        float4 v = { h[4*c], h[4*c+1], h[4*c+2], h[4*c+3] };
        ho[c] = v;
    }
}

// ---------- readout MLP: 32 -> 256 (selu) -> 256 (selu) -> 1 ----------
// block = 256 threads handles PB=32 paths; register-tiled layer-2 GEMM.
__global__ __launch_bounds__(256) void readout_kernel(
    const float* __restrict__ path_state,
    const float* __restrict__ R1, const float* __restrict__ Rb1,
    const float* __restrict__ R2, const float* __restrict__ Rb2,
    const float* __restrict__ R3, const float* __restrict__ Rb3,
    float* __restrict__ out)
{
    const int PB  = 32;
    const int STR = 260;                 // h1 row stride (floats), [p][j] layout
    __shared__ float h0s[PB * DIM];      // 4 KB
    __shared__ float h1s[PB * STR];      // ~33.3 KB
    __shared__ float outAcc[PB];
    int t  = threadIdx.x;
    int p0 = blockIdx.x * PB;            // NP % 32 == 0, no tail

    for (int i = t; i < PB * DIM; i += 256)
        h0s[i] = path_state[(size_t)p0 * DIM + i];
    if (t < PB) outAcc[t] = 0.0f;
    __syncthreads();

    // layer 1: thread t computes hidden column j=t for all 32 paths
    {
        int j = t;
        float r1[DIM];
        #pragma unroll
        for (int k = 0; k < DIM; ++k) r1[k] = R1[k * 256 + j];
        float bj = Rb1[j];
        for (int p = 0; p < PB; ++p) {
            float s = bj;
            #pragma unroll
            for (int k = 0; k < DIM; ++k) s += h0s[p * DIM + k] * r1[k];
            h1s[p * STR + j] = seluf(s);   // lanes write consecutive j: conflict-free
        }
    }
    __syncthreads();

    // layer 2: thread tile = 4 paths x 8 cols; k chunked by 4 for b128 LDS reads
    int tj = t & 31, tp = t >> 5;
    int j0 = tj * 8, pp0 = tp * 4;
    float acc[4][8];
    #pragma unroll
    for (int pi = 0; pi < 4; ++pi)
        #pragma unroll
        for (int ji = 0; ji < 8; ++ji) acc[pi][ji] = Rb2[j0 + ji];

    for (int k = 0; k < 256; k += 4) {
        float xv[4][4];
        #pragma unroll
        for (int pi = 0; pi < 4; ++pi) {
            float4 v = *(const float4*)&h1s[(pp0 + pi) * STR + k];
            xv[pi][0] = v.x; xv[pi][1] = v.y; xv[pi][2] = v.z; xv[pi][3] = v.w;
        }
        #pragma unroll
        for (int kk = 0; kk < 4; ++kk) {
            float wv[8];
            #pragma unroll
            for (int ji = 0; ji < 8; ++ji) wv[ji] = R2[(k + kk) * 256 + j0 + ji];
            #pragma unroll
            for (int pi = 0; pi < 4; ++pi)
                #pragma unroll
                for (int ji = 0; ji < 8; ++ji)
                    acc[pi][ji] += xv[pi][kk] * wv[ji];
        }
    }

    // selu + layer 3 partial dot, LDS-atomic reduce across the 32 j-groups
    float r3[8];
    #pragma unroll
    for (int ji = 0; ji < 8; ++ji) r3[ji] = R3[j0 + ji];
    #pragma unroll
    for (int pi = 0; pi < 4; ++pi) {
        float s = 0.0f;
        #pragma unroll
        for (int ji = 0; ji < 8; ++ji) s += seluf(acc[pi][ji]) * r3[ji];
        atomicAdd(&outAcc[pp0 + pi], s);
    }
    __syncthreads();
    if (t < PB) out[p0 + t] = outAcc[t] + Rb3[0];
}

extern "C" void kernel_launch(void* const* d_in, const int* in_sizes, int n_in,
                              void* d_out, int out_size, void* d_ws, size_t ws_size,
                              hipStream_t stream)
{
    const int*   links = (const int*)d_in[0];
    // d_in[1] = paths, d_in[2] = seqs: deterministic (e = p*5+l), not needed
    const float* cap = (const float*)d_in[3];
    const float* pol = (const float*)d_in[4];
    const float* wts = (const float*)d_in[5];
    const float* bw  = (const float*)d_in[6];
    const float* tos = (const float*)d_in[7];
    const float* pk  = (const float*)d_in[8];
    const float* avg = (const float*)d_in[9];
    const float* Wp  = (const float*)d_in[10];
    const float* Up  = (const float*)d_in[11];
    const float* bp  = (const float*)d_in[12];
    const float* Wl  = (const float*)d_in[13];
    const float* Ul  = (const float*)d_in[14];
    const float* bl  = (const float*)d_in[15];
    const float* R1  = (const float*)d_in[16];
    const float* Rb1 = (const float*)d_in[17];
    const float* R2  = (const float*)d_in[18];
    const float* Rb2 = (const float*)d_in[19];
    const float* R3  = (const float*)d_in[20];
    const float* Rb3 = (const float*)d_in[21];

    float* path_state = (float*)d_ws;                         // NP*32 f32      = 12.8 MB
    float* link_state = path_state + (size_t)NP * DIM;        // NLINKS*32 f32  = 1.28 MB
    float* msg        = link_state + (size_t)NLINKS * DIM;    // NLINKS*32 f32  = 1.28 MB

    init_kernel<<<(NP + 255) / 256, 256, 0, stream>>>(cap, pol, wts, bw, tos, pk, avg,
                                                      link_state, path_state);
    for (int it = 0; it < TITERS; ++it) {
        hipMemsetAsync(msg, 0, (size_t)NLINKS * DIM * sizeof(float), stream);
        path_kernel<<<(NP + 63) / 64, 64, 0, stream>>>(links, Wp, Up, bp,
                                                       link_state, path_state, msg);
        link_kernel<<<(NLINKS + 63) / 64, 64, 0, stream>>>(Wl, Ul, bl, msg, link_state);
    }
    readout_kernel<<<NP / 32, 256, 0, stream>>>(path_state, R1, Rb1, R2, Rb2, R3, Rb3,
                                                (float*)d_out);
}

// Round 5
// 8332.162 us; speedup vs baseline: 2.4552x; 2.4552x over previous
//
#include <hip/hip_runtime.h>
#include <hip/hip_bf16.h>

#define NP     100000   // n_paths
#define PLEN   5        // path length
#define NLINKS 10000    // n_links
#define DIM    32       // state dim
#define TITERS 8        // message passing iterations
#define E_TOT  (NP * PLEN)

// ---------- helpers ----------
__device__ __forceinline__ float fast_sigmoid(float v) {
    return 1.0f / (1.0f + __expf(-v));
}
__device__ __forceinline__ float fast_tanh(float v) {
    float e = __expf(-2.0f * fabsf(v));
    float t = (1.0f - e) / (1.0f + e);
    return v >= 0.0f ? t : -t;
}
__device__ __forceinline__ float seluf(float v) {
    const float sc = 1.0507009873554805f;
    const float al = 1.6732632423543772f;
    return v > 0.0f ? sc * v : sc * al * (__expf(v) - 1.0f);
}

// ---------- full GRU (links only; 10k rows, cheap) ----------
__device__ __forceinline__ void gru32(const float* __restrict__ W,
                                      const float* __restrict__ U,
                                      const float* __restrict__ b,
                                      const float (&x)[DIM], float (&h)[DIM])
{
    float z[DIM], r[DIM], hn[DIM];
    #pragma unroll
    for (int j = 0; j < DIM; ++j) {
        float sz = b[j]      + b[96 + j];
        float sr = b[32 + j] + b[96 + 32 + j];
        #pragma unroll
        for (int k = 0; k < DIM; ++k) {
            sz += x[k] * W[k * 96 + j]      + h[k] * U[k * 96 + j];
            sr += x[k] * W[k * 96 + 32 + j] + h[k] * U[k * 96 + 32 + j];
        }
        z[j] = fast_sigmoid(sz);
        r[j] = fast_sigmoid(sr);
    }
    #pragma unroll
    for (int j = 0; j < DIM; ++j) {
        float xn = b[64 + j];
        float hg = b[96 + 64 + j];
        #pragma unroll
        for (int k = 0; k < DIM; ++k) {
            xn += x[k] * W[k * 96 + 64 + j];
            hg += h[k] * U[k * 96 + 64 + j];
        }
        hn[j] = fast_tanh(xn + r[j] * hg);
    }
    #pragma unroll
    for (int j = 0; j < DIM; ++j)
        h[j] = z[j] * h[j] + (1.0f - z[j]) * hn[j];
}

// ---------- init ----------
__global__ __launch_bounds__(256) void init_kernel(
    const float* __restrict__ cap, const float* __restrict__ pol, const float* __restrict__ wts,
    const float* __restrict__ bw,  const float* __restrict__ tos,
    const float* __restrict__ pk,  const float* __restrict__ avg,
    float* __restrict__ link_state, float* __restrict__ path_state)
{
    int i = blockIdx.x * 256 + threadIdx.x;
    if (i < NLINKS) {
        float row[DIM];
        #pragma unroll
        for (int c = 0; c < DIM; ++c) row[c] = 0.0f;
        row[0] = cap[i]; row[1] = pol[i]; row[2] = wts[i];
        float4* o = (float4*)(link_state + (size_t)i * DIM);
        #pragma unroll
        for (int c = 0; c < 8; ++c) {
            float4 v = { row[4*c], row[4*c+1], row[4*c+2], row[4*c+3] };
            o[c] = v;
        }
    }
    if (i < NP) {
        float row[DIM];
        #pragma unroll
        for (int c = 0; c < DIM; ++c) row[c] = 0.0f;
        row[0] = bw[i]; row[1] = tos[i]; row[2] = pk[i]; row[3] = avg[i];
        float4* o = (float4*)(path_state + (size_t)i * DIM);
        #pragma unroll
        for (int c = 0; c < 8; ++c) {
            float4 v = { row[4*c], row[4*c+1], row[4*c+2], row[4*c+3] };
            o[c] = v;
        }
    }
}

// ---------- CSR build (links launch-invariant: build once per launch) ----------
__global__ __launch_bounds__(256) void csr_count(const int* __restrict__ links,
                                                 int* __restrict__ cnt)
{
    int e = blockIdx.x * 256 + threadIdx.x;
    if (e < E_TOT) atomicAdd(&cnt[links[e]], 1);
}

__global__ __launch_bounds__(256) void csr_scan(const int* __restrict__ cnt,
                                                int* __restrict__ row_start,
                                                int* __restrict__ cursor)
{
    __shared__ int s[256];
    int t = threadIdx.x;
    int carry = 0;
    for (int base = 0; base < NLINKS; base += 256) {
        int i = base + t;
        int v = (i < NLINKS) ? cnt[i] : 0;
        s[t] = v;
        __syncthreads();
        for (int off = 1; off < 256; off <<= 1) {
            int tv = (t >= off) ? s[t - off] : 0;
            __syncthreads();
            s[t] += tv;
            __syncthreads();
        }
        int excl = s[t] - v;
        if (i < NLINKS) { row_start[i] = carry + excl; cursor[i] = carry + excl; }
        int tot = s[255];
        __syncthreads();
        carry += tot;
    }
    if (t == 0) row_start[NLINKS] = carry;   // == E_TOT
}

__global__ __launch_bounds__(256) void csr_scatter(const int* __restrict__ links,
                                                   int* __restrict__ cursor,
                                                   int* __restrict__ eid)
{
    int e = blockIdx.x * 256 + threadIdx.x;
    if (e < E_TOT) {
        int slot = atomicAdd(&cursor[links[e]], 1);
        eid[slot] = e;
    }
}

// ---------- per-iteration: xg = link_state @ Wp + bp[0]  [NL,96] ----------
__global__ __launch_bounds__(256) void xg_kernel(const float* __restrict__ link_state,
                                                 const float* __restrict__ Wp,
                                                 const float* __restrict__ bp,
                                                 float* __restrict__ xg)
{
    int i = blockIdx.x * 256 + threadIdx.x;
    if (i >= NLINKS) return;
    float x[DIM];
    const float4* xv = (const float4*)(link_state + (size_t)i * DIM);
    #pragma unroll
    for (int c = 0; c < 8; ++c) {
        float4 v = xv[c];
        x[4*c] = v.x; x[4*c+1] = v.y; x[4*c+2] = v.z; x[4*c+3] = v.w;
    }
    for (int j0 = 0; j0 < 96; j0 += 4) {
        float s0 = bp[j0], s1 = bp[j0+1], s2 = bp[j0+2], s3 = bp[j0+3];
        #pragma unroll
        for (int k = 0; k < DIM; ++k) {
            float xk = x[k];
            s0 += xk * Wp[k * 96 + j0];
            s1 += xk * Wp[k * 96 + j0 + 1];
            s2 += xk * Wp[k * 96 + j0 + 2];
            s3 += xk * Wp[k * 96 + j0 + 3];
        }
        float4 v = { s0, s1, s2, s3 };
        *(float4*)&xg[(size_t)i * 96 + j0] = v;
    }
}

// ---------- path GRU over 5 hops; per-hop h -> m[E,32] (f32) ----------
template <bool STORE_M>
__global__ __launch_bounds__(64) void path_kernel(
    const int*   __restrict__ links,
    const float* __restrict__ xg,
    const float* __restrict__ Up, const float* __restrict__ bp,
    float* __restrict__ path_state,
    float* __restrict__ m)
{
    int p = blockIdx.x * 64 + threadIdx.x;
    if (p >= NP) return;
    float h[DIM];
    const float4* hv = (const float4*)(path_state + (size_t)p * DIM);
    #pragma unroll
    for (int i = 0; i < 8; ++i) {
        float4 v = hv[i];
        h[4*i] = v.x; h[4*i+1] = v.y; h[4*i+2] = v.z; h[4*i+3] = v.w;
    }
    int lk[PLEN];
    #pragma unroll
    for (int l = 0; l < PLEN; ++l) lk[l] = links[p * PLEN + l];

    #pragma unroll 1
    for (int l = 0; l < PLEN; ++l) {
        const float* xr = xg + (size_t)lk[l] * 96;
        float xzr[64];
        {
            const float4* x4 = (const float4*)xr;
            #pragma unroll
            for (int i = 0; i < 16; ++i) {
                float4 v = x4[i];
                xzr[4*i] = v.x; xzr[4*i+1] = v.y; xzr[4*i+2] = v.z; xzr[4*i+3] = v.w;
            }
        }
        float z[DIM], r[DIM];
        #pragma unroll
        for (int j = 0; j < DIM; ++j) {
            float sz = xzr[j]      + bp[96 + j];
            float sr = xzr[32 + j] + bp[96 + 32 + j];
            #pragma unroll
            for (int k = 0; k < DIM; ++k) {
                sz += h[k] * Up[k * 96 + j];
                sr += h[k] * Up[k * 96 + 32 + j];
            }
            z[j] = fast_sigmoid(sz);
            r[j] = fast_sigmoid(sr);
        }
        float xn[DIM];
        {
            const float4* x4 = (const float4*)(xr + 64);
            #pragma unroll
            for (int i = 0; i < 8; ++i) {
                float4 v = x4[i];
                xn[4*i] = v.x; xn[4*i+1] = v.y; xn[4*i+2] = v.z; xn[4*i+3] = v.w;
            }
        }
        float hn[DIM];
        #pragma unroll
        for (int j = 0; j < DIM; ++j) {
            float hg = bp[96 + 64 + j];
            #pragma unroll
            for (int k = 0; k < DIM; ++k)
                hg += h[k] * Up[k * 96 + 64 + j];
            hn[j] = fast_tanh(xn[j] + r[j] * hg);
        }
        #pragma unroll
        for (int j = 0; j < DIM; ++j)
            h[j] = z[j] * h[j] + (1.0f - z[j]) * hn[j];

        if (STORE_M) {
            float4* m4 = (float4*)(m + (size_t)(p * PLEN + l) * DIM);
            #pragma unroll
            for (int i = 0; i < 8; ++i) {
                float4 v = { h[4*i], h[4*i+1], h[4*i+2], h[4*i+3] };
                m4[i] = v;
            }
        }
    }
    float4* ho = (float4*)(path_state + (size_t)p * DIM);
    #pragma unroll
    for (int i = 0; i < 8; ++i) {
        float4 v = { h[4*i], h[4*i+1], h[4*i+2], h[4*i+3] };
        ho[i] = v;
    }
}

// ---------- CSR gather: msg[link] = sum over entries of m[e] ----------
__global__ __launch_bounds__(256) void agg_kernel(
    const int* __restrict__ row_start, const int* __restrict__ eid,
    const float* __restrict__ m, float* __restrict__ msg)
{
    int gid  = blockIdx.x * 256 + threadIdx.x;
    int link = gid >> 6;
    int lane = threadIdx.x & 63;
    if (link >= NLINKS) return;
    int s0 = row_start[link], s1 = row_start[link + 1];
    int half = lane >> 5, d = lane & 31;
    float v = 0.0f;
    for (int i = s0 + half; i < s1; i += 2) {
        int e = eid[i];
        v += m[(size_t)e * DIM + d];
    }
    v += __shfl_down(v, 32);
    if (lane < 32) msg[(size_t)link * DIM + d] = v;
}

// ---------- link GRU ----------
__global__ __launch_bounds__(64) void link_kernel(
    const float* __restrict__ Wl, const float* __restrict__ Ul, const float* __restrict__ bl,
    const float* __restrict__ msg,
    float* __restrict__ link_state)
{
    int i = blockIdx.x * 64 + threadIdx.x;
    if (i >= NLINKS) return;
    float h[DIM], x[DIM];
    const float4* xv = (const float4*)(msg + (size_t)i * DIM);
    const float4* hv = (const float4*)(link_state + (size_t)i * DIM);
    #pragma unroll
    for (int c = 0; c < 8; ++c) {
        float4 a = xv[c];
        x[4*c] = a.x; x[4*c+1] = a.y; x[4*c+2] = a.z; x[4*c+3] = a.w;
        float4 b2 = hv[c];
        h[4*c] = b2.x; h[4*c+1] = b2.y; h[4*c+2] = b2.z; h[4*c+3] = b2.w;
    }
    gru32(Wl, Ul, bl, x, h);
    float4* ho = (float4*)(link_state + (size_t)i * DIM);
    #pragma unroll
    for (int c = 0; c < 8; ++c) {
        float4 v = { h[4*c], h[4*c+1], h[4*c+2], h[4*c+3] };
        ho[c] = v;
    }
}

// ---------- readout MLP: 32 -> 256 (selu) -> 256 (selu) -> 1 ----------
__global__ __launch_bounds__(256) void readout_kernel(
    const float* __restrict__ path_state,
    const float* __restrict__ R1, const float* __restrict__ Rb1,
    const float* __restrict__ R2, const float* __restrict__ Rb2,
    const float* __restrict__ R3, const float* __restrict__ Rb3,
    float* __restrict__ out)
{
    const int PB  = 32;
    const int STR = 260;                 // h1 row stride (floats)
    __shared__ float h0s[PB * DIM];
    __shared__ float h1s[PB * STR];
    __shared__ float outAcc[PB];
    int t  = threadIdx.x;
    int p0 = blockIdx.x * PB;

    for (int i = t; i < PB * DIM; i += 256)
        h0s[i] = path_state[(size_t)p0 * DIM + i];
    if (t < PB) outAcc[t] = 0.0f;
    __syncthreads();

    {
        int j = t;
        float r1[DIM];
        #pragma unroll
        for (int k = 0; k < DIM; ++k) r1[k] = R1[k * 256 + j];
        float bj = Rb1[j];
        for (int p = 0; p < PB; ++p) {
            float s = bj;
            #pragma unroll
            for (int k = 0; k < DIM; ++k) s += h0s[p * DIM + k] * r1[k];
            h1s[p * STR + j] = seluf(s);
        }
    }
    __syncthreads();

    int tj = t & 31, tp = t >> 5;
    int j0 = tj * 8, pp0 = tp * 4;
    float acc[4][8];
    #pragma unroll
    for (int pi = 0; pi < 4; ++pi)
        #pragma unroll
        for (int ji = 0; ji < 8; ++ji) acc[pi][ji] = Rb2[j0 + ji];

    for (int k = 0; k < 256; k += 4) {
        float xv[4][4];
        #pragma unroll
        for (int pi = 0; pi < 4; ++pi) {
            float4 v = *(const float4*)&h1s[(pp0 + pi) * STR + k];
            xv[pi][0] = v.x; xv[pi][1] = v.y; xv[pi][2] = v.z; xv[pi][3] = v.w;
        }
        #pragma unroll
        for (int kk = 0; kk < 4; ++kk) {
            float wv[8];
            #pragma unroll
            for (int ji = 0; ji < 8; ++ji) wv[ji] = R2[(k + kk) * 256 + j0 + ji];
            #pragma unroll
            for (int pi = 0; pi < 4; ++pi)
                #pragma unroll
                for (int ji = 0; ji < 8; ++ji)
                    acc[pi][ji] += xv[pi][kk] * wv[ji];
        }
    }

    float r3[8];
    #pragma unroll
    for (int ji = 0; ji < 8; ++ji) r3[ji] = R3[j0 + ji];
    #pragma unroll
    for (int pi = 0; pi < 4; ++pi) {
        float s = 0.0f;
        #pragma unroll
        for (int ji = 0; ji < 8; ++ji) s += seluf(acc[pi][ji]) * r3[ji];
        atomicAdd(&outAcc[pp0 + pi], s);
    }
    __syncthreads();
    if (t < PB) out[p0 + t] = outAcc[t] + Rb3[0];
}

extern "C" void kernel_launch(void* const* d_in, const int* in_sizes, int n_in,
                              void* d_out, int out_size, void* d_ws, size_t ws_size,
                              hipStream_t stream)
{
    const int*   links = (const int*)d_in[0];
    const float* cap = (const float*)d_in[3];
    const float* pol = (const float*)d_in[4];
    const float* wts = (const float*)d_in[5];
    const float* bw  = (const float*)d_in[6];
    const float* tos = (const float*)d_in[7];
    const float* pk  = (const float*)d_in[8];
    const float* avg = (const float*)d_in[9];
    const float* Wp  = (const float*)d_in[10];
    const float* Up  = (const float*)d_in[11];
    const float* bp  = (const float*)d_in[12];
    const float* Wl  = (const float*)d_in[13];
    const float* Ul  = (const float*)d_in[14];
    const float* bl  = (const float*)d_in[15];
    const float* R1  = (const float*)d_in[16];
    const float* Rb1 = (const float*)d_in[17];
    const float* R2  = (const float*)d_in[18];
    const float* Rb2 = (const float*)d_in[19];
    const float* R3  = (const float*)d_in[20];
    const float* Rb3 = (const float*)d_in[21];

    // workspace layout (256B aligned chunks), ~85 MB total
    char* w = (char*)d_ws;
    size_t off = 0;
    auto alloc = [&](size_t bytes) {
        char* p = w + off;
        off += (bytes + 255) & ~(size_t)255;
        return p;
    };
    float* path_state = (float*)alloc((size_t)NP * DIM * 4);        // 12.8 MB
    float* link_state = (float*)alloc((size_t)NLINKS * DIM * 4);    // 1.28 MB
    float* msg        = (float*)alloc((size_t)NLINKS * DIM * 4);    // 1.28 MB
    float* xg         = (float*)alloc((size_t)NLINKS * 96 * 4);     // 3.84 MB
    float* m          = (float*)alloc((size_t)E_TOT * DIM * 4);     // 64 MB
    int*   cnt        = (int*)alloc((size_t)NLINKS * 4);
    int*   row_start  = (int*)alloc((size_t)(NLINKS + 1) * 4);
    int*   cursor     = (int*)alloc((size_t)NLINKS * 4);
    int*   eid        = (int*)alloc((size_t)E_TOT * 4);             // 2 MB

    init_kernel<<<(NP + 255) / 256, 256, 0, stream>>>(cap, pol, wts, bw, tos, pk, avg,
                                                      link_state, path_state);
    // CSR (links constant across iterations -> build once per launch)
    hipMemsetAsync(cnt, 0, (size_t)NLINKS * 4, stream);
    csr_count  <<<(E_TOT + 255) / 256, 256, 0, stream>>>(links, cnt);
    csr_scan   <<<1, 256, 0, stream>>>(cnt, row_start, cursor);
    csr_scatter<<<(E_TOT + 255) / 256, 256, 0, stream>>>(links, cursor, eid);

    for (int it = 0; it < TITERS; ++it) {
        xg_kernel<<<(NLINKS + 255) / 256, 256, 0, stream>>>(link_state, Wp, bp, xg);
        if (it < TITERS - 1) {
            path_kernel<true><<<(NP + 63) / 64, 64, 0, stream>>>(links, xg, Up, bp,
                                                                 path_state, m);
            agg_kernel <<<(NLINKS * 64 + 255) / 256, 256, 0, stream>>>(row_start, eid, m, msg);
            link_kernel<<<(NLINKS + 63) / 64, 64, 0, stream>>>(Wl, Ul, bl, msg, link_state);
        } else {
            // last iteration: link update is dead (readout reads only path_state)
            path_kernel<false><<<(NP + 63) / 64, 64, 0, stream>>>(links, xg, Up, bp,
                                                                  path_state, m);
        }
    }
    readout_kernel<<<NP / 32, 256, 0, stream>>>(path_state, R1, Rb1, R2, Rb2, R3, Rb3,
                                                (float*)d_out);
}

// Round 6
// 3411.021 us; speedup vs baseline: 5.9974x; 2.4427x over previous
//
#include <hip/hip_runtime.h>
#include <hip/hip_bf16.h>

#define NP     100000   // n_paths
#define PLEN   5        // path length
#define NLINKS 10000    // n_links
#define DIM    32       // state dim
#define TITERS 8        // message passing iterations
#define E_TOT  (NP * PLEN)

// ---------- helpers ----------
__device__ __forceinline__ float fast_sigmoid(float v) {
    return 1.0f / (1.0f + __expf(-v));
}
__device__ __forceinline__ float fast_tanh(float v) {
    float e = __expf(-2.0f * fabsf(v));
    float t = (1.0f - e) / (1.0f + e);
    return v >= 0.0f ? t : -t;
}
__device__ __forceinline__ float seluf(float v) {
    const float sc = 1.0507009873554805f;
    const float al = 1.6732632423543772f;
    return v > 0.0f ? sc * v : sc * al * (__expf(v) - 1.0f);
}

// ---------- init ----------
__global__ __launch_bounds__(256) void init_kernel(
    const float* __restrict__ cap, const float* __restrict__ pol, const float* __restrict__ wts,
    const float* __restrict__ bw,  const float* __restrict__ tos,
    const float* __restrict__ pk,  const float* __restrict__ avg,
    float* __restrict__ link_state, float* __restrict__ path_state)
{
    int i = blockIdx.x * 256 + threadIdx.x;
    if (i < NLINKS) {
        float row[DIM];
        #pragma unroll
        for (int c = 0; c < DIM; ++c) row[c] = 0.0f;
        row[0] = cap[i]; row[1] = pol[i]; row[2] = wts[i];
        float4* o = (float4*)(link_state + (size_t)i * DIM);
        #pragma unroll
        for (int c = 0; c < 8; ++c) {
            float4 v = { row[4*c], row[4*c+1], row[4*c+2], row[4*c+3] };
            o[c] = v;
        }
    }
    if (i < NP) {
        float row[DIM];
        #pragma unroll
        for (int c = 0; c < DIM; ++c) row[c] = 0.0f;
        row[0] = bw[i]; row[1] = tos[i]; row[2] = pk[i]; row[3] = avg[i];
        float4* o = (float4*)(path_state + (size_t)i * DIM);
        #pragma unroll
        for (int c = 0; c < 8; ++c) {
            float4 v = { row[4*c], row[4*c+1], row[4*c+2], row[4*c+3] };
            o[c] = v;
        }
    }
}

// ---------- CSR build (links launch-invariant) ----------
__global__ __launch_bounds__(256) void csr_count(const int* __restrict__ links,
                                                 int* __restrict__ cnt)
{
    int e = blockIdx.x * 256 + threadIdx.x;
    if (e < E_TOT) atomicAdd(&cnt[links[e]], 1);
}

__global__ __launch_bounds__(256) void csr_scan(const int* __restrict__ cnt,
                                                int* __restrict__ row_start,
                                                int* __restrict__ cursor)
{
    __shared__ int s[256];
    int t = threadIdx.x;
    int carry = 0;
    for (int base = 0; base < NLINKS; base += 256) {
        int i = base + t;
        int v = (i < NLINKS) ? cnt[i] : 0;
        s[t] = v;
        __syncthreads();
        for (int off = 1; off < 256; off <<= 1) {
            int tv = (t >= off) ? s[t - off] : 0;
            __syncthreads();
            s[t] += tv;
            __syncthreads();
        }
        int excl = s[t] - v;
        if (i < NLINKS) { row_start[i] = carry + excl; cursor[i] = carry + excl; }
        int tot = s[255];
        __syncthreads();
        carry += tot;
    }
    if (t == 0) row_start[NLINKS] = carry;   // == E_TOT
}

__global__ __launch_bounds__(256) void csr_scatter(const int* __restrict__ links,
                                                   int* __restrict__ cursor,
                                                   int* __restrict__ eid)
{
    int e = blockIdx.x * 256 + threadIdx.x;
    if (e < E_TOT) {
        int slot = atomicAdd(&cursor[links[e]], 1);
        eid[slot] = e;
    }
}

// ---------- per-iteration: xg = link_state @ Wp + bp[0]  [NL,96] ----------
__global__ __launch_bounds__(256) void xg_kernel(const float* __restrict__ link_state,
                                                 const float* __restrict__ Wp,
                                                 const float* __restrict__ bp,
                                                 float* __restrict__ xg)
{
    int i = blockIdx.x * 256 + threadIdx.x;
    if (i >= NLINKS) return;
    float x[DIM];
    const float4* xv = (const float4*)(link_state + (size_t)i * DIM);
    #pragma unroll
    for (int c = 0; c < 8; ++c) {
        float4 v = xv[c];
        x[4*c] = v.x; x[4*c+1] = v.y; x[4*c+2] = v.z; x[4*c+3] = v.w;
    }
    for (int j0 = 0; j0 < 96; j0 += 4) {
        float s0 = bp[j0], s1 = bp[j0+1], s2 = bp[j0+2], s3 = bp[j0+3];
        #pragma unroll
        for (int k = 0; k < DIM; ++k) {
            float xk = x[k];
            s0 += xk * Wp[k * 96 + j0];
            s1 += xk * Wp[k * 96 + j0 + 1];
            s2 += xk * Wp[k * 96 + j0 + 2];
            s3 += xk * Wp[k * 96 + j0 + 3];
        }
        float4 v = { s0, s1, s2, s3 };
        *(float4*)&xg[(size_t)i * 96 + j0] = v;
    }
}

// ---------- path GRU over 5 hops; per-hop h -> m[E,32] (f32) ----------
// k-outer / j-inner: Up[k*96+j] is wave-uniform & consecutive in j -> s_load
// vectors; h[k] is one broadcast VGPR per 32 FMAs. Gates sequential (z,r,n)
// keeps peak live regs ~150; launch_bounds(256,1) lifts VGPR cap to 512 so
// nothing spills (R5 had 124 VGPR vs ~224 live -> scratch thrash, 749us).
template <bool STORE_M>
__global__ __launch_bounds__(256, 1) void path_kernel(
    const int*   __restrict__ links,
    const float* __restrict__ xg,
    const float* __restrict__ Up, const float* __restrict__ bp,
    float* __restrict__ path_state,
    float* __restrict__ m)
{
    int p = blockIdx.x * 256 + threadIdx.x;
    if (p >= NP) return;
    float h[DIM];
    {
        const float4* hv = (const float4*)(path_state + (size_t)p * DIM);
        #pragma unroll
        for (int i = 0; i < 8; ++i) {
            float4 v = hv[i];
            h[4*i] = v.x; h[4*i+1] = v.y; h[4*i+2] = v.z; h[4*i+3] = v.w;
        }
    }
    #pragma unroll 1
    for (int l = 0; l < PLEN; ++l) {
        int link = links[p * PLEN + l];
        const float* xr = xg + (size_t)link * 96;
        float acc[DIM], z[DIM], r[DIM];

        // ---- z gate: acc = xz + b_rz ; += h @ Up[:,0:32] ----
        #pragma unroll
        for (int i = 0; i < 8; ++i) {
            float4 v = ((const float4*)xr)[i];
            acc[4*i]   = v.x + bp[96 + 4*i];
            acc[4*i+1] = v.y + bp[96 + 4*i+1];
            acc[4*i+2] = v.z + bp[96 + 4*i+2];
            acc[4*i+3] = v.w + bp[96 + 4*i+3];
        }
        #pragma unroll
        for (int k = 0; k < DIM; ++k) {
            float hk = h[k];
            const float* u = Up + k * 96;
            #pragma unroll
            for (int j = 0; j < DIM; ++j) acc[j] += hk * u[j];
        }
        #pragma unroll
        for (int j = 0; j < DIM; ++j) z[j] = fast_sigmoid(acc[j]);

        // ---- r gate ----
        #pragma unroll
        for (int i = 0; i < 8; ++i) {
            float4 v = ((const float4*)(xr + 32))[i];
            acc[4*i]   = v.x + bp[96 + 32 + 4*i];
            acc[4*i+1] = v.y + bp[96 + 32 + 4*i+1];
            acc[4*i+2] = v.z + bp[96 + 32 + 4*i+2];
            acc[4*i+3] = v.w + bp[96 + 32 + 4*i+3];
        }
        #pragma unroll
        for (int k = 0; k < DIM; ++k) {
            float hk = h[k];
            const float* u = Up + k * 96 + 32;
            #pragma unroll
            for (int j = 0; j < DIM; ++j) acc[j] += hk * u[j];
        }
        #pragma unroll
        for (int j = 0; j < DIM; ++j) r[j] = fast_sigmoid(acc[j]);

        // ---- n gate recurrent part: acc = b_rn + h @ Up[:,64:96] ----
        #pragma unroll
        for (int j = 0; j < DIM; ++j) acc[j] = bp[96 + 64 + j];
        #pragma unroll
        for (int k = 0; k < DIM; ++k) {
            float hk = h[k];
            const float* u = Up + k * 96 + 64;
            #pragma unroll
            for (int j = 0; j < DIM; ++j) acc[j] += hk * u[j];
        }
        // stream xn, finish hn, update h (old h fully consumed above)
        #pragma unroll
        for (int i = 0; i < 8; ++i) {
            float4 v = ((const float4*)(xr + 64))[i];
            float hn0 = fast_tanh(v.x + r[4*i]   * acc[4*i]);
            float hn1 = fast_tanh(v.y + r[4*i+1] * acc[4*i+1]);
            float hn2 = fast_tanh(v.z + r[4*i+2] * acc[4*i+2]);
            float hn3 = fast_tanh(v.w + r[4*i+3] * acc[4*i+3]);
            h[4*i]   = z[4*i]   * h[4*i]   + (1.0f - z[4*i])   * hn0;
            h[4*i+1] = z[4*i+1] * h[4*i+1] + (1.0f - z[4*i+1]) * hn1;
            h[4*i+2] = z[4*i+2] * h[4*i+2] + (1.0f - z[4*i+2]) * hn2;
            h[4*i+3] = z[4*i+3] * h[4*i+3] + (1.0f - z[4*i+3]) * hn3;
        }

        if (STORE_M) {
            float4* m4 = (float4*)(m + (size_t)(p * PLEN + l) * DIM);
            #pragma unroll
            for (int i = 0; i < 8; ++i) {
                float4 v = { h[4*i], h[4*i+1], h[4*i+2], h[4*i+3] };
                m4[i] = v;
            }
        }
    }
    float4* ho = (float4*)(path_state + (size_t)p * DIM);
    #pragma unroll
    for (int i = 0; i < 8; ++i) {
        float4 v = { h[4*i], h[4*i+1], h[4*i+2], h[4*i+3] };
        ho[i] = v;
    }
}

// ---------- CSR gather: msg[link] = sum over entries of m[e] ----------
__global__ __launch_bounds__(256) void agg_kernel(
    const int* __restrict__ row_start, const int* __restrict__ eid,
    const float* __restrict__ m, float* __restrict__ msg)
{
    int gid  = blockIdx.x * 256 + threadIdx.x;
    int link = gid >> 6;
    int lane = threadIdx.x & 63;
    if (link >= NLINKS) return;
    int s0 = row_start[link], s1 = row_start[link + 1];
    int half = lane >> 5, d = lane & 31;
    float v = 0.0f;
    for (int i = s0 + half; i < s1; i += 2) {
        int e = eid[i];
        v += m[(size_t)e * DIM + d];
    }
    v += __shfl_down(v, 32);
    if (lane < 32) msg[(size_t)link * DIM + d] = v;
}

// ---------- link GRU (same k-outer low-pressure structure) ----------
__global__ __launch_bounds__(256, 1) void link_kernel(
    const float* __restrict__ Wl, const float* __restrict__ Ul, const float* __restrict__ bl,
    const float* __restrict__ msg,
    float* __restrict__ link_state)
{
    int i = blockIdx.x * 256 + threadIdx.x;
    if (i >= NLINKS) return;
    float h[DIM], x[DIM];
    {
        const float4* xv = (const float4*)(msg + (size_t)i * DIM);
        const float4* hv = (const float4*)(link_state + (size_t)i * DIM);
        #pragma unroll
        for (int c = 0; c < 8; ++c) {
            float4 a = xv[c];
            x[4*c] = a.x; x[4*c+1] = a.y; x[4*c+2] = a.z; x[4*c+3] = a.w;
            float4 b2 = hv[c];
            h[4*c] = b2.x; h[4*c+1] = b2.y; h[4*c+2] = b2.z; h[4*c+3] = b2.w;
        }
    }
    float acc[DIM], z[DIM], r[DIM];

    // z
    #pragma unroll
    for (int j = 0; j < DIM; ++j) acc[j] = bl[j] + bl[96 + j];
    #pragma unroll
    for (int k = 0; k < DIM; ++k) {
        float xk = x[k], hk = h[k];
        const float* wv = Wl + k * 96;
        const float* uv = Ul + k * 96;
        #pragma unroll
        for (int j = 0; j < DIM; ++j) acc[j] += xk * wv[j] + hk * uv[j];
    }
    #pragma unroll
    for (int j = 0; j < DIM; ++j) z[j] = fast_sigmoid(acc[j]);

    // r
    #pragma unroll
    for (int j = 0; j < DIM; ++j) acc[j] = bl[32 + j] + bl[96 + 32 + j];
    #pragma unroll
    for (int k = 0; k < DIM; ++k) {
        float xk = x[k], hk = h[k];
        const float* wv = Wl + k * 96 + 32;
        const float* uv = Ul + k * 96 + 32;
        #pragma unroll
        for (int j = 0; j < DIM; ++j) acc[j] += xk * wv[j] + hk * uv[j];
    }
    #pragma unroll
    for (int j = 0; j < DIM; ++j) r[j] = fast_sigmoid(acc[j]);

    // n: xn and hg must stay separate (hn = tanh(xn + r*hg))
    float accx[DIM];
    #pragma unroll
    for (int j = 0; j < DIM; ++j) { accx[j] = bl[64 + j]; acc[j] = bl[96 + 64 + j]; }
    #pragma unroll
    for (int k = 0; k < DIM; ++k) {
        float xk = x[k], hk = h[k];
        const float* wv = Wl + k * 96 + 64;
        const float* uv = Ul + k * 96 + 64;
        #pragma unroll
        for (int j = 0; j < DIM; ++j) {
            accx[j] += xk * wv[j];
            acc[j]  += hk * uv[j];
        }
    }
    #pragma unroll
    for (int j = 0; j < DIM; ++j) {
        float hn = fast_tanh(accx[j] + r[j] * acc[j]);
        h[j] = z[j] * h[j] + (1.0f - z[j]) * hn;
    }

    float4* ho = (float4*)(link_state + (size_t)i * DIM);
    #pragma unroll
    for (int c = 0; c < 8; ++c) {
        float4 v = { h[4*c], h[4*c+1], h[4*c+2], h[4*c+3] };
        ho[c] = v;
    }
}

// ---------- readout MLP: 32 -> 256 (selu) -> 256 (selu) -> 1 ----------
__global__ __launch_bounds__(256) void readout_kernel(
    const float* __restrict__ path_state,
    const float* __restrict__ R1, const float* __restrict__ Rb1,
    const float* __restrict__ R2, const float* __restrict__ Rb2,
    const float* __restrict__ R3, const float* __restrict__ Rb3,
    float* __restrict__ out)
{
    const int PB  = 32;
    const int STR = 260;                 // h1 row stride (floats)
    __shared__ float h0s[PB * DIM];
    __shared__ float h1s[PB * STR];
    __shared__ float outAcc[PB];
    int t  = threadIdx.x;
    int p0 = blockIdx.x * PB;

    for (int i = t; i < PB * DIM; i += 256)
        h0s[i] = path_state[(size_t)p0 * DIM + i];
    if (t < PB) outAcc[t] = 0.0f;
    __syncthreads();

    {
        int j = t;
        float r1[DIM];
        #pragma unroll
        for (int k = 0; k < DIM; ++k) r1[k] = R1[k * 256 + j];
        float bj = Rb1[j];
        for (int p = 0; p < PB; ++p) {
            float s = bj;
            #pragma unroll
            for (int k = 0; k < DIM; ++k) s += h0s[p * DIM + k] * r1[k];
            h1s[p * STR + j] = seluf(s);
        }
    }
    __syncthreads();

    int tj = t & 31, tp = t >> 5;
    int j0 = tj * 8, pp0 = tp * 4;
    float acc[4][8];
    #pragma unroll
    for (int pi = 0; pi < 4; ++pi)
        #pragma unroll
        for (int ji = 0; ji < 8; ++ji) acc[pi][ji] = Rb2[j0 + ji];

    for (int k = 0; k < 256; k += 4) {
        float xv[4][4];
        #pragma unroll
        for (int pi = 0; pi < 4; ++pi) {
            float4 v = *(const float4*)&h1s[(pp0 + pi) * STR + k];
            xv[pi][0] = v.x; xv[pi][1] = v.y; xv[pi][2] = v.z; xv[pi][3] = v.w;
        }
        #pragma unroll
        for (int kk = 0; kk < 4; ++kk) {
            float wv[8];
            #pragma unroll
            for (int ji = 0; ji < 8; ++ji) wv[ji] = R2[(k + kk) * 256 + j0 + ji];
            #pragma unroll
            for (int pi = 0; pi < 4; ++pi)
                #pragma unroll
                for (int ji = 0; ji < 8; ++ji)
                    acc[pi][ji] += xv[pi][kk] * wv[ji];
        }
    }

    float r3[8];
    #pragma unroll
    for (int ji = 0; ji < 8; ++ji) r3[ji] = R3[j0 + ji];
    #pragma unroll
    for (int pi = 0; pi < 4; ++pi) {
        float s = 0.0f;
        #pragma unroll
        for (int ji = 0; ji < 8; ++ji) s += seluf(acc[pi][ji]) * r3[ji];
        atomicAdd(&outAcc[pp0 + pi], s);
    }
    __syncthreads();
    if (t < PB) out[p0 + t] = outAcc[t] + Rb3[0];
}

extern "C" void kernel_launch(void* const* d_in, const int* in_sizes, int n_in,
                              void* d_out, int out_size, void* d_ws, size_t ws_size,
                              hipStream_t stream)
{
    const int*   links = (const int*)d_in[0];
    const float* cap = (const float*)d_in[3];
    const float* pol = (const float*)d_in[4];
    const float* wts = (const float*)d_in[5];
    const float* bw  = (const float*)d_in[6];
    const float* tos = (const float*)d_in[7];
    const float* pk  = (const float*)d_in[8];
    const float* avg = (const float*)d_in[9];
    const float* Wp  = (const float*)d_in[10];
    const float* Up  = (const float*)d_in[11];
    const float* bp  = (const float*)d_in[12];
    const float* Wl  = (const float*)d_in[13];
    const float* Ul  = (const float*)d_in[14];
    const float* bl  = (const float*)d_in[15];
    const float* R1  = (const float*)d_in[16];
    const float* Rb1 = (const float*)d_in[17];
    const float* R2  = (const float*)d_in[18];
    const float* Rb2 = (const float*)d_in[19];
    const float* R3  = (const float*)d_in[20];
    const float* Rb3 = (const float*)d_in[21];

    // workspace layout (256B aligned chunks), ~85 MB total
    char* w = (char*)d_ws;
    size_t off = 0;
    auto alloc = [&](size_t bytes) {
        char* p = w + off;
        off += (bytes + 255) & ~(size_t)255;
        return p;
    };
    float* path_state = (float*)alloc((size_t)NP * DIM * 4);        // 12.8 MB
    float* link_state = (float*)alloc((size_t)NLINKS * DIM * 4);    // 1.28 MB
    float* msg        = (float*)alloc((size_t)NLINKS * DIM * 4);    // 1.28 MB
    float* xg         = (float*)alloc((size_t)NLINKS * 96 * 4);     // 3.84 MB
    float* m          = (float*)alloc((size_t)E_TOT * DIM * 4);     // 64 MB
    int*   cnt        = (int*)alloc((size_t)NLINKS * 4);
    int*   row_start  = (int*)alloc((size_t)(NLINKS + 1) * 4);
    int*   cursor     = (int*)alloc((size_t)NLINKS * 4);
    int*   eid        = (int*)alloc((size_t)E_TOT * 4);             // 2 MB

    init_kernel<<<(NP + 255) / 256, 256, 0, stream>>>(cap, pol, wts, bw, tos, pk, avg,
                                                      link_state, path_state);
    // CSR (links constant across iterations -> build once per launch)
    hipMemsetAsync(cnt, 0, (size_t)NLINKS * 4, stream);
    csr_count  <<<(E_TOT + 255) / 256, 256, 0, stream>>>(links, cnt);
    csr_scan   <<<1, 256, 0, stream>>>(cnt, row_start, cursor);
    csr_scatter<<<(E_TOT + 255) / 256, 256, 0, stream>>>(links, cursor, eid);

    for (int it = 0; it < TITERS; ++it) {
        xg_kernel<<<(NLINKS + 255) / 256, 256, 0, stream>>>(link_state, Wp, bp, xg);
        if (it < TITERS - 1) {
            path_kernel<true><<<(NP + 255) / 256, 256, 0, stream>>>(links, xg, Up, bp,
                                                                    path_state, m);
            agg_kernel <<<(NLINKS * 64 + 255) / 256, 256, 0, stream>>>(row_start, eid, m, msg);
            link_kernel<<<(NLINKS + 255) / 256, 256, 0, stream>>>(Wl, Ul, bl, msg, link_state);
        } else {
            // last iteration: link update is dead (readout reads only path_state)
            path_kernel<false><<<(NP + 255) / 256, 256, 0, stream>>>(links, xg, Up, bp,
                                                                     path_state, m);
        }
    }
    readout_kernel<<<NP / 32, 256, 0, stream>>>(path_state, R1, Rb1, R2, Rb2, R3, Rb3,
                                                (float*)d_out);
}